// Round 4
// baseline (197.523 us; speedup 1.0000x reference)
//
#include <hip/hip_runtime.h>

typedef __attribute__((ext_vector_type(8))) __bf16 bf16x8;
typedef __attribute__((ext_vector_type(4))) float f32x4;
typedef unsigned short ushortT;

#define Bn 4
#define Hn 128
#define Wn 128
#define HP 130
#define WP 130

#define XP_ELEMS (Bn * HP * WP * 64)   // 4,326,400 ushorts
#define WCAT_ELEMS (64 * 576)

__device__ __forceinline__ ushortT f2bf_u(float f) {
    unsigned int u = __float_as_uint(f);
    return (ushortT)((u + 0x8000u) >> 16);   // round-half-up to bf16
}

// ---------------------------------------------------------------------------
// prep: blocks 0..519 = pad x -> NHWC bf16 (130x130 zero border)
//       blocks 520..663 = repack wcat, 664..807 = repack wreg
// wcatB[ch][kpos*64+c]; ch: 0..17 fc1 | 18..35 fc2 | 36..53 off | 54..62 mod
// wregB[o][kpos*64+c]
// ---------------------------------------------------------------------------
__global__ __launch_bounds__(256) void prep(
    const float* __restrict__ x,
    const float* __restrict__ w1, const float* __restrict__ w2,
    const float* __restrict__ wo, const float* __restrict__ wm,
    const float* __restrict__ wr,
    ushortT* __restrict__ xp, ushortT* __restrict__ wcatB, ushortT* __restrict__ wregB)
{
    __shared__ float tl[64][129];
    int blk = blockIdx.x;
    int tid = threadIdx.x;

    if (blk < 520) {
        int b = blk / HP;
        int y = blk - b * HP;
        size_t rowbase = (size_t)(b * HP + y) * (WP * 64);
        uint* rowu = (uint*)(xp + rowbase);
        if (y == 0 || y == HP - 1) {
            for (int i = tid; i < WP * 32; i += 256) rowu[i] = 0u;
            return;
        }
        for (int i = tid; i < 64 * 128; i += 256) {
            int c = i >> 7, w = i & 127;
            tl[c][w] = x[((size_t)(b * 64 + c) * Hn + (y - 1)) * Wn + w];
        }
        __syncthreads();
        if (tid < 32) rowu[tid] = 0u;                       // left border col
        else if (tid < 64) rowu[129 * 32 + (tid - 32)] = 0u; // right border col
        for (int i = tid; i < 128 * 32; i += 256) {
            int w = i >> 5, cp = i & 31;
            uint u = (uint)f2bf_u(tl[2 * cp][w]) | ((uint)f2bf_u(tl[2 * cp + 1][w]) << 16);
            rowu[(w + 1) * 32 + cp] = u;
        }
    } else if (blk < 664) {
        int t = (blk - 520) * 256 + tid;      // 0..36863
        int ch = t / 576;
        int k = t - ch * 576;
        int kpos = k >> 6, c = k & 63;
        float v = 0.f;
        if (ch < 18)      v = w1[(ch * 64 + c) * 9 + kpos];
        else if (ch < 36) v = w2[((ch - 18) * 64 + c) * 9 + kpos];
        else if (ch < 54) v = wo[((ch - 36) * 64 + c) * 9 + kpos];
        else if (ch < 63) v = wm[((ch - 54) * 64 + c) * 9 + kpos];
        wcatB[t] = f2bf_u(v);
    } else {
        int t = (blk - 664) * 256 + tid;
        int o = t / 576;
        int k = t - o * 576;
        int kpos = k >> 6, c = k & 63;
        wregB[t] = f2bf_u(wr[(o * 64 + c) * 9 + kpos]);
    }
}

// ---------------------------------------------------------------------------
// Fused, one wave per block, 16 pixels per wave. Grid = 4*128*8 = 4096.
// All LDS traffic is wave-local (Cls transpose, corner tables).
// MFMA 16x16x32 bf16: A row=lane&15,k=(lane>>4)*8+j; B col=lane&15 same k;
// D col=lane&15, row=(lane>>4)*4+reg.
// ---------------------------------------------------------------------------
__global__ __launch_bounds__(64) void fused16(
    const ushortT* __restrict__ xp, const float* __restrict__ eps,
    const float* __restrict__ b1, const float* __restrict__ b2,
    const float* __restrict__ bo, const float* __restrict__ bm,
    const ushortT* __restrict__ wcatB, const ushortT* __restrict__ wregB,
    float* __restrict__ out)
{
    __shared__ float  Cls[16 * 65];     // conv results [pix][ch], stride 65
    __shared__ int4   cOffL[9 * 16];    // per (k,pix): 4 corner elem-offsets
    __shared__ float4 cWgtL[9 * 16];    // per (k,pix): bilinear*mask weights

    int blk = blockIdx.x;               // b*1024 + h*8 + t
    int t = blk & 7;
    int h = (blk >> 3) & 127;
    int b = blk >> 10;
    int l = threadIdx.x;
    int lane15 = l & 15;
    int g4 = l >> 4;
    int kl8 = g4 << 3;
    int wcol = t << 4;

    const f32x4 zero4 = {0.f, 0.f, 0.f, 0.f};
    f32x4 acc[4];
#pragma unroll
    for (int mt = 0; mt < 4; ++mt) acc[mt] = zero4;

    // ---------------- Phase 1: conv GEMM (M=64, N=16, K=576) ----------------
#pragma unroll
    for (int kpos = 0; kpos < 9; ++kpos) {
        const int ky = kpos / 3, kx = kpos % 3;
        const ushortT* arow = wcatB + kpos * 64 + kl8;
        const ushortT* xrow = xp + (size_t)(b * HP + h + ky) * (WP * 64);
        const ushortT* bp = xrow + (size_t)(wcol + lane15 + kx) * 64 + kl8;
#pragma unroll
        for (int ks = 0; ks < 2; ++ks) {
            bf16x8 bfr = *(const bf16x8*)(bp + ks * 32);
#pragma unroll
            for (int mt = 0; mt < 4; ++mt) {
                bf16x8 afr = *(const bf16x8*)(arow + (mt * 16 + lane15) * 576 + ks * 32);
                acc[mt] = __builtin_amdgcn_mfma_f32_16x16x32_bf16(afr, bfr, acc[mt], 0, 0, 0);
            }
        }
    }

    // conv C -> LDS transposed [pix][ch]
#pragma unroll
    for (int mt = 0; mt < 4; ++mt)
#pragma unroll
        for (int r = 0; r < 4; ++r)
            Cls[lane15 * 65 + mt * 16 + g4 * 4 + r] = acc[mt][r];
    __syncthreads();

    // ---------------- Phase 2: gating, (k,pix) items across all 64 lanes ----
#pragma unroll
    for (int kk = 0; kk < 3; ++kk) {
        int item = kk * 64 + l;
        int k = item >> 4;          // 0..11
        int pix = item & 15;
        if (k < 9) {
            int ky = k / 3, kx = k % 3;
            int w = wcol + pix;
            const float* crow = Cls + pix * 65;
            float offv[2];
#pragma unroll
            for (int d = 0; d < 2; ++d) {
                int ch = 2 * k + d;
                float mu = fmaxf(crow[ch] + b1[ch], 0.f);
                float lv = fmaxf(crow[18 + ch] + b2[ch], 0.f);
                float e  = eps[((size_t)(b * 18 + ch) * Hn + h) * Wn + w];
                float z  = fmaf(e, __expf(0.5f * lv), mu);
                float gate = 1.f / (1.f + __expf(-z));
                offv[d] = (crow[36 + ch] + bo[ch]) * gate;
            }
            float m = 2.f / (1.f + __expf(-(crow[54 + k] + bm[k])));
            float py = (float)(h + ky - 1) + offv[0];
            float px = (float)(w + kx - 1) + offv[1];
            float y0f = floorf(py), x0f = floorf(px);
            float ly = py - y0f, lx = px - x0f;
            int y0 = (int)y0f, x0 = (int)x0f;
            int y1 = y0 + 1, x1 = x0 + 1;
            bool okY0 = (y0 >= 0) & (y0 < Hn);
            bool okY1 = (y1 >= 0) & (y1 < Hn);
            bool okX0 = (x0 >= 0) & (x0 < Wn);
            bool okX1 = (x1 >= 0) & (x1 < Wn);
            int y0c = min(max(y0, 0), Hn - 1) + 1, y1c = min(max(y1, 0), Hn - 1) + 1;
            int x0c = min(max(x0, 0), Wn - 1) + 1, x1c = min(max(x1, 0), Wn - 1) + 1;
            int rb = b * HP;
            int4 co;
            co.x = ((rb + y0c) * WP + x0c) * 64;
            co.y = ((rb + y0c) * WP + x1c) * 64;
            co.z = ((rb + y1c) * WP + x0c) * 64;
            co.w = ((rb + y1c) * WP + x1c) * 64;
            float4 wq;
            wq.x = (1.f - ly) * (1.f - lx) * ((okY0 & okX0) ? m : 0.f);
            wq.y = (1.f - ly) * lx         * ((okY0 & okX1) ? m : 0.f);
            wq.z = ly * (1.f - lx)         * ((okY1 & okX0) ? m : 0.f);
            wq.w = ly * lx                 * ((okY1 & okX1) ? m : 0.f);
            cOffL[k * 16 + pix] = co;
            cWgtL[k * 16 + pix] = wq;
        }
    }
    __syncthreads();

    // ---------------- Phase 3: gather + deform GEMM ----------------
    f32x4 dcc[4];
#pragma unroll
    for (int mt = 0; mt < 4; ++mt) dcc[mt] = zero4;

#pragma unroll
    for (int kpos = 0; kpos < 9; ++kpos) {
        const ushortT* arow = wregB + kpos * 64 + kl8;
        int4 co   = cOffL[kpos * 16 + lane15];
        float4 wq = cWgtL[kpos * 16 + lane15];
#pragma unroll
        for (int ks = 0; ks < 2; ++ks) {
            int cofs = ks * 32 + kl8;
            bf16x8 v00 = *(const bf16x8*)(xp + co.x + cofs);
            bf16x8 v01 = *(const bf16x8*)(xp + co.y + cofs);
            bf16x8 v10 = *(const bf16x8*)(xp + co.z + cofs);
            bf16x8 v11 = *(const bf16x8*)(xp + co.w + cofs);
            bf16x8 bfr;
#pragma unroll
            for (int j = 0; j < 8; ++j) {
                float f = wq.x * (float)v00[j];
                f = fmaf(wq.y, (float)v01[j], f);
                f = fmaf(wq.z, (float)v10[j], f);
                f = fmaf(wq.w, (float)v11[j], f);
                bfr[j] = (__bf16)f;
            }
#pragma unroll
            for (int mt = 0; mt < 4; ++mt) {
                bf16x8 afr = *(const bf16x8*)(arow + (mt * 16 + lane15) * 576 + ks * 32);
                dcc[mt] = __builtin_amdgcn_mfma_f32_16x16x32_bf16(afr, bfr, dcc[mt], 0, 0, 0);
            }
        }
    }

    // ---------------- Phase 4: write out ----------------
#pragma unroll
    for (int mt = 0; mt < 4; ++mt)
#pragma unroll
        for (int r = 0; r < 4; ++r) {
            int o = mt * 16 + g4 * 4 + r;
            out[((size_t)(b * 64 + o) * Hn + h) * Wn + wcol + lane15] = dcc[mt][r];
        }
}

// ---------------------------------------------------------------------------
extern "C" void kernel_launch(void* const* d_in, const int* in_sizes, int n_in,
                              void* d_out, int out_size, void* d_ws, size_t ws_size,
                              hipStream_t stream) {
    const float* x     = (const float*)d_in[0];
    const float* eps   = (const float*)d_in[1];
    const float* w_fc1 = (const float*)d_in[2];
    const float* b_fc1 = (const float*)d_in[3];
    const float* w_fc2 = (const float*)d_in[4];
    const float* b_fc2 = (const float*)d_in[5];
    const float* w_off = (const float*)d_in[6];
    const float* b_off = (const float*)d_in[7];
    const float* w_mod = (const float*)d_in[8];
    const float* b_mod = (const float*)d_in[9];
    const float* w_reg = (const float*)d_in[10];

    ushortT* xp    = (ushortT*)d_ws;
    ushortT* wcatB = xp + XP_ELEMS;
    ushortT* wregB = wcatB + WCAT_ELEMS;

    prep<<<808, 256, 0, stream>>>(x, w_fc1, w_fc2, w_off, w_mod, w_reg,
                                  xp, wcatB, wregB);
    fused16<<<Bn * Hn * 8, 64, 0, stream>>>(xp, eps, b_fc1, b_fc2, b_off, b_mod,
                                            wcatB, wregB, (float*)d_out);
}

// Round 5
// 193.425 us; speedup vs baseline: 1.0212x; 1.0212x over previous
//
#include <hip/hip_runtime.h>

typedef __attribute__((ext_vector_type(8))) __bf16 bf16x8;
typedef __attribute__((ext_vector_type(4))) float f32x4;
typedef unsigned short ushortT;

#define Bn 4
#define Hn 128
#define Wn 128
#define HP 130
#define WP 130

#define XP_ELEMS (Bn * HP * WP * 64)   // 4,326,400 ushorts
#define WCAT_ELEMS (64 * 576)

__device__ __forceinline__ ushortT f2bf_u(float f) {
    unsigned int u = __float_as_uint(f);
    return (ushortT)((u + 0x8000u) >> 16);   // round-half-up to bf16
}

// ---------------------------------------------------------------------------
// prep2: blocks 0..2079   = pad x -> NHWC bf16 (130x130 zero border), 1/4 row each
//        blocks 2080..2223 = repack wcat, 2224..2367 = repack wreg
// wcatB[ch][kpos*64+c]; ch: 0..17 fc1 | 18..35 fc2 | 36..53 off | 54..62 mod
// wregB[o][kpos*64+c]
// ---------------------------------------------------------------------------
__global__ __launch_bounds__(256) void prep2(
    const float* __restrict__ x,
    const float* __restrict__ w1, const float* __restrict__ w2,
    const float* __restrict__ wo, const float* __restrict__ wm,
    const float* __restrict__ wr,
    ushortT* __restrict__ xp, ushortT* __restrict__ wcatB, ushortT* __restrict__ wregB)
{
    __shared__ float tl[64][33];
    int blk = blockIdx.x;
    int tid = threadIdx.x;

    if (blk < 2080) {
        int rowid = blk >> 2;
        int q = blk & 3;
        int b = rowid / HP;
        int y = rowid - b * HP;
        size_t rowbase = (size_t)(b * HP + y) * (WP * 64);
        uint* rowu = (uint*)(xp + rowbase);
        if (y == 0 || y == HP - 1) {
            for (int i = tid; i < 1040; i += 256) rowu[q * 1040 + i] = 0u;
            return;
        }
        int w0 = q * 32;
        for (int i = tid; i < 2048; i += 256) {
            int c = i >> 5, w = i & 31;
            tl[c][w] = x[((size_t)(b * 64 + c) * Hn + (y - 1)) * Wn + w0 + w];
        }
        __syncthreads();
        if (q == 0 && tid < 32) rowu[tid] = 0u;                  // left border
        if (q == 3 && tid < 32) rowu[129 * 32 + tid] = 0u;       // right border
        for (int i = tid; i < 1024; i += 256) {
            int w = i >> 5, cp = i & 31;
            uint u = (uint)f2bf_u(tl[2 * cp][w]) | ((uint)f2bf_u(tl[2 * cp + 1][w]) << 16);
            rowu[(w0 + w + 1) * 32 + cp] = u;
        }
    } else if (blk < 2224) {
        int t = (blk - 2080) * 256 + tid;      // 0..36863
        int ch = t / 576;
        int k = t - ch * 576;
        int kpos = k >> 6, c = k & 63;
        float v = 0.f;
        if (ch < 18)      v = w1[(ch * 64 + c) * 9 + kpos];
        else if (ch < 36) v = w2[((ch - 18) * 64 + c) * 9 + kpos];
        else if (ch < 54) v = wo[((ch - 36) * 64 + c) * 9 + kpos];
        else if (ch < 63) v = wm[((ch - 54) * 64 + c) * 9 + kpos];
        wcatB[t] = f2bf_u(v);
    } else {
        int t = (blk - 2224) * 256 + tid;
        int o = t / 576;
        int k = t - o * 576;
        int kpos = k >> 6, c = k & 63;
        wregB[t] = f2bf_u(wr[(o * 64 + c) * 9 + kpos]);
    }
}

// ---------------------------------------------------------------------------
// FusedK: 256 threads = 4 waves, each wave owns 16 pixels (wave-local MFMA
// data path identical to r4's fused16). Block covers 64 pixels (half a row).
// Grid = 4*128*2 = 1024 = 4 blocks/CU; LDS 35 KB -> exactly 4 resident.
// MFMA 16x16x32 bf16: A row=lane&15,k=(lane>>4)*8+j; B col=lane&15 same k;
// D col=lane&15, row=(lane>>4)*4+reg.
// ---------------------------------------------------------------------------
__global__ __launch_bounds__(256, 4) void fusedK(
    const ushortT* __restrict__ xp, const float* __restrict__ eps,
    const float* __restrict__ b1, const float* __restrict__ b2,
    const float* __restrict__ bo, const float* __restrict__ bm,
    const ushortT* __restrict__ wcatB, const ushortT* __restrict__ wregB,
    float* __restrict__ out)
{
    __shared__ float  Cls[64 * 65];     // conv results [pixL][ch], stride 65
    __shared__ int4   cOffL[9 * 64];    // per (k,pixL): 4 corner elem-offsets
    __shared__ float4 cWgtL[9 * 64];    // per (k,pixL): bilinear*mask weights

    int blk = blockIdx.x;               // b*256 + h*2 + half
    int half = blk & 1;
    int h = (blk >> 1) & 127;
    int b = blk >> 8;
    int tid = threadIdx.x;
    int l = tid & 63;
    int wv = tid >> 6;
    int lane15 = l & 15;
    int g4 = l >> 4;
    int kl8 = g4 << 3;
    int wcol = half * 64 + wv * 16;     // global w of this wave's pixel 0
    int pixL0 = wv * 16;                // block-local pixel base

    const f32x4 zero4 = {0.f, 0.f, 0.f, 0.f};
    f32x4 acc[4];
#pragma unroll
    for (int mt = 0; mt < 4; ++mt) acc[mt] = zero4;

    // ---------------- Phase 1: conv GEMM (M=64, N=16/wave, K=576) ----------
#pragma unroll
    for (int kpos = 0; kpos < 9; ++kpos) {
        const int ky = kpos / 3, kx = kpos % 3;
        const ushortT* arow = wcatB + kpos * 64 + kl8;
        const ushortT* xrow = xp + (size_t)(b * HP + h + ky) * (WP * 64);
        const ushortT* bp = xrow + (size_t)(wcol + lane15 + kx) * 64 + kl8;
#pragma unroll
        for (int ks = 0; ks < 2; ++ks) {
            bf16x8 bfr = *(const bf16x8*)(bp + ks * 32);
#pragma unroll
            for (int mt = 0; mt < 4; ++mt) {
                bf16x8 afr = *(const bf16x8*)(arow + (mt * 16 + lane15) * 576 + ks * 32);
                acc[mt] = __builtin_amdgcn_mfma_f32_16x16x32_bf16(afr, bfr, acc[mt], 0, 0, 0);
            }
        }
    }

    // conv C -> LDS transposed [pixL][ch]
#pragma unroll
    for (int mt = 0; mt < 4; ++mt)
#pragma unroll
        for (int r = 0; r < 4; ++r)
            Cls[(pixL0 + lane15) * 65 + mt * 16 + g4 * 4 + r] = acc[mt][r];
    __syncthreads();

    // ---------------- Phase 2: gating, 576 (k,pixL) items over 256 threads --
#pragma unroll
    for (int kk = 0; kk < 3; ++kk) {
        int item = kk * 256 + tid;
        if (item < 576) {
            int k = item >> 6;          // 0..8
            int pix = item & 63;
            int ky = k / 3, kx = k % 3;
            int w = half * 64 + pix;
            const float* crow = Cls + pix * 65;
            float offv[2];
#pragma unroll
            for (int d = 0; d < 2; ++d) {
                int ch = 2 * k + d;
                float mu = fmaxf(crow[ch] + b1[ch], 0.f);
                float lv = fmaxf(crow[18 + ch] + b2[ch], 0.f);
                float e  = eps[((size_t)(b * 18 + ch) * Hn + h) * Wn + w];
                float z  = fmaf(e, __expf(0.5f * lv), mu);
                float gate = 1.f / (1.f + __expf(-z));
                offv[d] = (crow[36 + ch] + bo[ch]) * gate;
            }
            float m = 2.f / (1.f + __expf(-(crow[54 + k] + bm[k])));
            float py = (float)(h + ky - 1) + offv[0];
            float px = (float)(w + kx - 1) + offv[1];
            float y0f = floorf(py), x0f = floorf(px);
            float ly = py - y0f, lx = px - x0f;
            int y0 = (int)y0f, x0 = (int)x0f;
            int y1 = y0 + 1, x1 = x0 + 1;
            bool okY0 = (y0 >= 0) & (y0 < Hn);
            bool okY1 = (y1 >= 0) & (y1 < Hn);
            bool okX0 = (x0 >= 0) & (x0 < Wn);
            bool okX1 = (x1 >= 0) & (x1 < Wn);
            int y0c = min(max(y0, 0), Hn - 1) + 1, y1c = min(max(y1, 0), Hn - 1) + 1;
            int x0c = min(max(x0, 0), Wn - 1) + 1, x1c = min(max(x1, 0), Wn - 1) + 1;
            int rb = b * HP;
            int4 co;
            co.x = ((rb + y0c) * WP + x0c) * 64;
            co.y = ((rb + y0c) * WP + x1c) * 64;
            co.z = ((rb + y1c) * WP + x0c) * 64;
            co.w = ((rb + y1c) * WP + x1c) * 64;
            float4 wq;
            wq.x = (1.f - ly) * (1.f - lx) * ((okY0 & okX0) ? m : 0.f);
            wq.y = (1.f - ly) * lx         * ((okY0 & okX1) ? m : 0.f);
            wq.z = ly * (1.f - lx)         * ((okY1 & okX0) ? m : 0.f);
            wq.w = ly * lx                 * ((okY1 & okX1) ? m : 0.f);
            cOffL[k * 64 + pix] = co;
            cWgtL[k * 64 + pix] = wq;
        }
    }
    __syncthreads();

    // ---------------- Phase 3: gather + deform GEMM ----------------
    f32x4 dcc[4];
#pragma unroll
    for (int mt = 0; mt < 4; ++mt) dcc[mt] = zero4;

#pragma unroll
    for (int kpos = 0; kpos < 9; ++kpos) {
        const ushortT* arow = wregB + kpos * 64 + kl8;
        int4 co   = cOffL[kpos * 64 + pixL0 + lane15];
        float4 wq = cWgtL[kpos * 64 + pixL0 + lane15];
#pragma unroll
        for (int ks = 0; ks < 2; ++ks) {
            int cofs = ks * 32 + kl8;
            bf16x8 v00 = *(const bf16x8*)(xp + co.x + cofs);
            bf16x8 v01 = *(const bf16x8*)(xp + co.y + cofs);
            bf16x8 v10 = *(const bf16x8*)(xp + co.z + cofs);
            bf16x8 v11 = *(const bf16x8*)(xp + co.w + cofs);
            bf16x8 bfr;
#pragma unroll
            for (int j = 0; j < 8; ++j) {
                float f = wq.x * (float)v00[j];
                f = fmaf(wq.y, (float)v01[j], f);
                f = fmaf(wq.z, (float)v10[j], f);
                f = fmaf(wq.w, (float)v11[j], f);
                bfr[j] = (__bf16)f;
            }
#pragma unroll
            for (int mt = 0; mt < 4; ++mt) {
                bf16x8 afr = *(const bf16x8*)(arow + (mt * 16 + lane15) * 576 + ks * 32);
                dcc[mt] = __builtin_amdgcn_mfma_f32_16x16x32_bf16(afr, bfr, dcc[mt], 0, 0, 0);
            }
        }
    }

    // ---------------- Phase 4: write out ----------------
#pragma unroll
    for (int mt = 0; mt < 4; ++mt)
#pragma unroll
        for (int r = 0; r < 4; ++r) {
            int o = mt * 16 + g4 * 4 + r;
            out[((size_t)(b * 64 + o) * Hn + h) * Wn + wcol + lane15] = dcc[mt][r];
        }
}

// ---------------------------------------------------------------------------
extern "C" void kernel_launch(void* const* d_in, const int* in_sizes, int n_in,
                              void* d_out, int out_size, void* d_ws, size_t ws_size,
                              hipStream_t stream) {
    const float* x     = (const float*)d_in[0];
    const float* eps   = (const float*)d_in[1];
    const float* w_fc1 = (const float*)d_in[2];
    const float* b_fc1 = (const float*)d_in[3];
    const float* w_fc2 = (const float*)d_in[4];
    const float* b_fc2 = (const float*)d_in[5];
    const float* w_off = (const float*)d_in[6];
    const float* b_off = (const float*)d_in[7];
    const float* w_mod = (const float*)d_in[8];
    const float* b_mod = (const float*)d_in[9];
    const float* w_reg = (const float*)d_in[10];

    ushortT* xp    = (ushortT*)d_ws;
    ushortT* wcatB = xp + XP_ELEMS;
    ushortT* wregB = wcatB + WCAT_ELEMS;

    prep2<<<2368, 256, 0, stream>>>(x, w_fc1, w_fc2, w_off, w_mod, w_reg,
                                    xp, wcatB, wregB);
    fusedK<<<1024, 256, 0, stream>>>(xp, eps, b_fc1, b_fc2, b_off, b_mod,
                                     wcatB, wregB, (float*)d_out);
}

// Round 6
// 167.946 us; speedup vs baseline: 1.1761x; 1.1517x over previous
//
#include <hip/hip_runtime.h>

typedef __attribute__((ext_vector_type(8))) __bf16 bf16x8;
typedef __attribute__((ext_vector_type(4))) float f32x4;
typedef unsigned short ushortT;

#define Bn 4
#define Hn 128
#define Wn 128
#define HP 130
#define WP 130
#define HW (Hn * Wn)

#define XP_ELEMS (Bn * HP * WP * 64)   // ushorts
#define WCAT_ELEMS (64 * 576)

__device__ __forceinline__ ushortT f2bf_u(float f) {
    unsigned int u = __float_as_uint(f);
    return (ushortT)((u + 0x8000u) >> 16);   // round-half-up to bf16
}

// ---------------------------------------------------------------------------
// prep3:
//  blocks [0,1024)      : interior NHWC bf16 pad-transpose, 64 pixels x 64 ch
//  blocks [1024,1152)   : zero the 130x130 borders
//  blocks [1152,1296)   : repack wcat   (wcatB[ch][kpos*64+c])
//  blocks [1296,1440)   : repack wreg   (wregB[o][kpos*64+c])
// ---------------------------------------------------------------------------
__global__ __launch_bounds__(256) void prep3(
    const float* __restrict__ x,
    const float* __restrict__ w1, const float* __restrict__ w2,
    const float* __restrict__ wo, const float* __restrict__ wm,
    const float* __restrict__ wr,
    ushortT* __restrict__ xp, ushortT* __restrict__ wcatB, ushortT* __restrict__ wregB)
{
    __shared__ float tl[64][69];
    int blk = blockIdx.x;
    int tid = threadIdx.x;

    if (blk < 1024) {
        int b = blk >> 8;
        int chunk = blk & 255;
        int hw0 = chunk << 6;          // 64-pixel chunk, fixed row
        int y = hw0 >> 7;              // source row
        int w0 = hw0 & 127;            // 0 or 64
        const float* xb = x + (size_t)b * 64 * HW + hw0;
        for (int i = tid; i < 4096; i += 256) {
            int c = i >> 6, w = i & 63;               // coalesced 256B in w
            tl[w][c] = xb[(size_t)c * HW + w];
        }
        __syncthreads();
        uint2* dst = (uint2*)(xp + ((size_t)(b * HP + y + 1) * WP + (w0 + 1)) * 64);
        for (int j = tid; j < 1024; j += 256) {       // consecutive j -> consecutive addr
            int w = j >> 4, cp = j & 15;
            uint2 u;
            u.x = (uint)f2bf_u(tl[w][4 * cp])     | ((uint)f2bf_u(tl[w][4 * cp + 1]) << 16);
            u.y = (uint)f2bf_u(tl[w][4 * cp + 2]) | ((uint)f2bf_u(tl[w][4 * cp + 3]) << 16);
            dst[j] = u;
        }
    } else if (blk < 1152) {
        int idx = (blk - 1024) * 256 + tid;           // [0, 32768)
        if (idx < 16512) {
            int b, y, w, e;
            if (idx < 8320) {                         // rows y=0,129 (130 px each)
                int p = idx >> 3; e = idx & 7;
                b = p / 260; int rr = p - b * 260;
                y = (rr < 130) ? 0 : (HP - 1);
                w = (rr < 130) ? rr : (rr - 130);
            } else {                                  // cols w=0,129, y=1..128
                int g = idx - 8320;
                int p = g >> 3; e = g & 7;
                b = p >> 8; int rr = p & 255;
                y = 1 + (rr & 127);
                w = (rr < 128) ? 0 : (WP - 1);
            }
            uint4 z = {0u, 0u, 0u, 0u};
            ((uint4*)xp)[((size_t)(b * HP + y) * WP + w) * 8 + e] = z;
        }
    } else if (blk < 1296) {
        int t = (blk - 1152) * 256 + tid;             // 0..36863
        int ch = t / 576;
        int k = t - ch * 576;
        int kpos = k >> 6, c = k & 63;
        float v = 0.f;
        if (ch < 18)      v = w1[(ch * 64 + c) * 9 + kpos];
        else if (ch < 36) v = w2[((ch - 18) * 64 + c) * 9 + kpos];
        else if (ch < 54) v = wo[((ch - 36) * 64 + c) * 9 + kpos];
        else if (ch < 63) v = wm[((ch - 54) * 64 + c) * 9 + kpos];
        wcatB[t] = f2bf_u(v);
    } else {
        int t = (blk - 1296) * 256 + tid;
        int o = t / 576;
        int k = t - o * 576;
        int kpos = k >> 6, c = k & 63;
        wregB[t] = f2bf_u(wr[(o * 64 + c) * 9 + kpos]);
    }
}

// ---------------------------------------------------------------------------
// fusedN: block = 256 thr (4 waves) = one image row (128 pixels).
// Wave wv owns 32 pixels (nt=2 subtiles of 16). All frag loads batched
// before MFMAs for ILP. Grid = 512 with bijective XCD swizzle.
// MFMA 16x16x32 bf16: A row=lane&15,k=(lane>>4)*8+j; B col=lane&15 same k;
// D col=lane&15, row=(lane>>4)*4+reg.
// ---------------------------------------------------------------------------
__global__ __launch_bounds__(256, 2) void fusedN(
    const ushortT* __restrict__ xp, const float* __restrict__ eps,
    const float* __restrict__ b1, const float* __restrict__ b2,
    const float* __restrict__ bo, const float* __restrict__ bm,
    const ushortT* __restrict__ wcatB, const ushortT* __restrict__ wregB,
    float* __restrict__ out)
{
    __shared__ float  Cls[128 * 65];    // conv results [pix][ch]
    __shared__ int4   cOffL[9 * 128];   // per (k,pix): 4 corner elem-offsets
    __shared__ float4 cWgtL[9 * 128];   // per (k,pix): bilinear*mask weights

    // bijective XCD swizzle: 512 % 8 == 0
    int bid = blockIdx.x;
    int blk = (bid & 7) * 64 + (bid >> 3);
    int h = blk & 127;
    int b = blk >> 7;
    int tid = threadIdx.x;
    int l = tid & 63;
    int wv = tid >> 6;
    int lane15 = l & 15;
    int g4 = l >> 4;
    int kl8 = g4 << 3;
    int p0 = wv << 5;                   // wave's pixel base (0..96)

    const f32x4 zero4 = {0.f, 0.f, 0.f, 0.f};
    f32x4 acc[4][2];
#pragma unroll
    for (int mt = 0; mt < 4; ++mt) { acc[mt][0] = zero4; acc[mt][1] = zero4; }

    // ---------------- Phase 1: conv GEMM (M=64, N=32/wave, K=576) ----------
#pragma unroll
    for (int kpos = 0; kpos < 9; ++kpos) {
        const int ky = kpos / 3, kx = kpos % 3;
        const ushortT* arow = wcatB + kpos * 64 + kl8;
        const ushortT* xrow = xp + (size_t)(b * HP + h + ky) * (WP * 64);

        bf16x8 afr[4][2];
#pragma unroll
        for (int mt = 0; mt < 4; ++mt)
#pragma unroll
            for (int ks = 0; ks < 2; ++ks)
                afr[mt][ks] = *(const bf16x8*)(arow + (mt * 16 + lane15) * 576 + ks * 32);

        bf16x8 bfr[2][2];
#pragma unroll
        for (int nt = 0; nt < 2; ++nt) {
            const ushortT* bp = xrow + (size_t)(p0 + nt * 16 + lane15 + kx) * 64 + kl8;
#pragma unroll
            for (int ks = 0; ks < 2; ++ks)
                bfr[nt][ks] = *(const bf16x8*)(bp + ks * 32);
        }

#pragma unroll
        for (int nt = 0; nt < 2; ++nt)
#pragma unroll
            for (int ks = 0; ks < 2; ++ks)
#pragma unroll
                for (int mt = 0; mt < 4; ++mt)
                    acc[mt][nt] = __builtin_amdgcn_mfma_f32_16x16x32_bf16(afr[mt][ks], bfr[nt][ks], acc[mt][nt], 0, 0, 0);
    }

    // conv C -> LDS transposed [pix][ch]
#pragma unroll
    for (int nt = 0; nt < 2; ++nt)
#pragma unroll
        for (int mt = 0; mt < 4; ++mt)
#pragma unroll
            for (int r = 0; r < 4; ++r)
                Cls[(p0 + nt * 16 + lane15) * 65 + mt * 16 + g4 * 4 + r] = acc[mt][nt][r];
    __syncthreads();

    // ---------------- Phase 2: gating, 1152 (k,pix) items over 256 threads --
#pragma unroll
    for (int kk = 0; kk < 5; ++kk) {
        int item = kk * 256 + tid;
        if (item < 1152) {
            int k = item >> 7;          // 0..8
            int pix = item & 127;
            int ky = k / 3, kx = k % 3;
            const float* crow = Cls + pix * 65;
            float offv[2];
#pragma unroll
            for (int d = 0; d < 2; ++d) {
                int ch = 2 * k + d;
                float mu = fmaxf(crow[ch] + b1[ch], 0.f);
                float lv = fmaxf(crow[18 + ch] + b2[ch], 0.f);
                float e  = eps[((size_t)(b * 18 + ch) * Hn + h) * Wn + pix];
                float z  = fmaf(e, __expf(0.5f * lv), mu);
                float gate = 1.f / (1.f + __expf(-z));
                offv[d] = (crow[36 + ch] + bo[ch]) * gate;
            }
            float m = 2.f / (1.f + __expf(-(crow[54 + k] + bm[k])));
            float py = (float)(h + ky - 1) + offv[0];
            float px = (float)(pix + kx - 1) + offv[1];
            float y0f = floorf(py), x0f = floorf(px);
            float ly = py - y0f, lx = px - x0f;
            int y0 = (int)y0f, x0 = (int)x0f;
            int y1 = y0 + 1, x1 = x0 + 1;
            bool okY0 = (y0 >= 0) & (y0 < Hn);
            bool okY1 = (y1 >= 0) & (y1 < Hn);
            bool okX0 = (x0 >= 0) & (x0 < Wn);
            bool okX1 = (x1 >= 0) & (x1 < Wn);
            int y0c = min(max(y0, 0), Hn - 1) + 1, y1c = min(max(y1, 0), Hn - 1) + 1;
            int x0c = min(max(x0, 0), Wn - 1) + 1, x1c = min(max(x1, 0), Wn - 1) + 1;
            int rb = b * HP;
            int4 co;
            co.x = ((rb + y0c) * WP + x0c) * 64;
            co.y = ((rb + y0c) * WP + x1c) * 64;
            co.z = ((rb + y1c) * WP + x0c) * 64;
            co.w = ((rb + y1c) * WP + x1c) * 64;
            float4 wq;
            wq.x = (1.f - ly) * (1.f - lx) * ((okY0 & okX0) ? m : 0.f);
            wq.y = (1.f - ly) * lx         * ((okY0 & okX1) ? m : 0.f);
            wq.z = ly * (1.f - lx)         * ((okY1 & okX0) ? m : 0.f);
            wq.w = ly * lx                 * ((okY1 & okX1) ? m : 0.f);
            cOffL[k * 128 + pix] = co;
            cWgtL[k * 128 + pix] = wq;
        }
    }
    __syncthreads();

    // ---------------- Phase 3: gather + deform GEMM ----------------
    f32x4 dcc[4][2];
#pragma unroll
    for (int mt = 0; mt < 4; ++mt) { dcc[mt][0] = zero4; dcc[mt][1] = zero4; }

#pragma unroll
    for (int kpos = 0; kpos < 9; ++kpos) {
        const ushortT* arow = wregB + kpos * 64 + kl8;
        bf16x8 afr[4][2];
#pragma unroll
        for (int mt = 0; mt < 4; ++mt)
#pragma unroll
            for (int ks = 0; ks < 2; ++ks)
                afr[mt][ks] = *(const bf16x8*)(arow + (mt * 16 + lane15) * 576 + ks * 32);

#pragma unroll
        for (int nt = 0; nt < 2; ++nt) {
            int pix = p0 + nt * 16 + lane15;
            int4 co   = cOffL[kpos * 128 + pix];
            float4 wq = cWgtL[kpos * 128 + pix];
            bf16x8 v00[2], v01[2], v10[2], v11[2];
#pragma unroll
            for (int ks = 0; ks < 2; ++ks) {
                int cofs = ks * 32 + kl8;
                v00[ks] = *(const bf16x8*)(xp + co.x + cofs);
                v01[ks] = *(const bf16x8*)(xp + co.y + cofs);
                v10[ks] = *(const bf16x8*)(xp + co.z + cofs);
                v11[ks] = *(const bf16x8*)(xp + co.w + cofs);
            }
#pragma unroll
            for (int ks = 0; ks < 2; ++ks) {
                bf16x8 bfr;
#pragma unroll
                for (int j = 0; j < 8; ++j) {
                    float f = wq.x * (float)v00[ks][j];
                    f = fmaf(wq.y, (float)v01[ks][j], f);
                    f = fmaf(wq.z, (float)v10[ks][j], f);
                    f = fmaf(wq.w, (float)v11[ks][j], f);
                    bfr[j] = (__bf16)f;
                }
#pragma unroll
                for (int mt = 0; mt < 4; ++mt)
                    dcc[mt][nt] = __builtin_amdgcn_mfma_f32_16x16x32_bf16(afr[mt][ks], bfr, dcc[mt][nt], 0, 0, 0);
            }
        }
    }

    // ---------------- Phase 4: write out ----------------
#pragma unroll
    for (int nt = 0; nt < 2; ++nt)
#pragma unroll
        for (int mt = 0; mt < 4; ++mt)
#pragma unroll
            for (int r = 0; r < 4; ++r) {
                int o = mt * 16 + g4 * 4 + r;
                out[((size_t)(b * 64 + o) * Hn + h) * Wn + p0 + nt * 16 + lane15] = dcc[mt][nt][r];
            }
}

// ---------------------------------------------------------------------------
extern "C" void kernel_launch(void* const* d_in, const int* in_sizes, int n_in,
                              void* d_out, int out_size, void* d_ws, size_t ws_size,
                              hipStream_t stream) {
    const float* x     = (const float*)d_in[0];
    const float* eps   = (const float*)d_in[1];
    const float* w_fc1 = (const float*)d_in[2];
    const float* b_fc1 = (const float*)d_in[3];
    const float* w_fc2 = (const float*)d_in[4];
    const float* b_fc2 = (const float*)d_in[5];
    const float* w_off = (const float*)d_in[6];
    const float* b_off = (const float*)d_in[7];
    const float* w_mod = (const float*)d_in[8];
    const float* b_mod = (const float*)d_in[9];
    const float* w_reg = (const float*)d_in[10];

    ushortT* xp    = (ushortT*)d_ws;
    ushortT* wcatB = xp + XP_ELEMS;
    ushortT* wregB = wcatB + WCAT_ELEMS;

    prep3<<<1440, 256, 0, stream>>>(x, w_fc1, w_fc2, w_off, w_mod, w_reg,
                                    xp, wcatB, wregB);
    fusedN<<<512, 256, 0, stream>>>(xp, eps, b_fc1, b_fc2, b_off, b_mod,
                                    wcatB, wregB, (float*)d_out);
}